// Round 18
// baseline (126.812 us; speedup 1.0000x reference)
//
#include <hip/hip_runtime.h>

#define HW 4096
#define CCH 256
#define MOFF 432
#define PTOT 32768
#define PDIM 68
#define PIMG (PDIM*PDIM)      // 4624 padded cells per group-plane (2-wide zero border)

typedef unsigned short u16;
typedef __attribute__((ext_vector_type(8))) short short8;
typedef __attribute__((ext_vector_type(8))) unsigned short u16x8;
typedef __attribute__((ext_vector_type(4))) float f32x4;

__device__ __forceinline__ u16 f2b(float f){
  unsigned int u = __float_as_uint(f);
  unsigned int rounding = 0x7FFFu + ((u >> 16) & 1u);
  return (u16)((u + rounding) >> 16);
}
__device__ __forceinline__ float b2f(u16 s){
  return __uint_as_float(((unsigned int)s) << 16);
}
// fragment-swizzled weight index: frag for o-tile n0=o>>4, k-chunk kf=k>>5;
// lane = (o&15) + 16*((k&31)>>3); elem j = k&7.
__device__ __forceinline__ size_t swz(int o, int k){
  return (size_t)((o >> 4) * 8 + (k >> 5)) * 512
       + ((o & 15) + (((k & 31) >> 3) << 4)) * 8 + (k & 7);
}

// ---------------------------------------------------------------------------
// k_prep: weight prep (direct fragment-swizzled stores) + BN fold + borders.
// grid 1553:
//  [0,256)     wbs <- w1 row o=r (swizzled)
//  [256,336)   wbs rows 688..767 = 0 (swizzled)
//  [336,592)   wb2s <- w2 row o=r-336 (swizzled)
//  592         BN fold
//  [593,1121)  h1p planar border zero
//  [1121,1553) wcomb row j: s = woff[j].w1 -> wbs row 256+j (swizzled); bcomb
// ---------------------------------------------------------------------------
__global__ __launch_bounds__(256) void k_prep(
    const float* __restrict__ w1, const float* __restrict__ w2,
    const float* __restrict__ woff, const float* __restrict__ b1,
    const float* __restrict__ boff,
    const float* __restrict__ gamma, const float* __restrict__ beta,
    const float* __restrict__ mean, const float* __restrict__ var,
    u16* __restrict__ wbs, u16* __restrict__ wb2s,
    float* __restrict__ bnA, float* __restrict__ bnB,
    float* __restrict__ bcomb, u16* __restrict__ h1p){
  __shared__ float sbuf[512];
  int r = blockIdx.x, t = threadIdx.x;
  if (r < 256){ wbs[swz(r, t)] = f2b(w1[r * 256 + t]); }
  else if (r < 336){ wbs[swz(688 + (r - 256), t)] = 0; }
  else if (r < 592){ int o = r - 336; wb2s[swz(o, t)] = f2b(w2[o * 256 + t]); }
  else if (r == 592){
    if (t < 256){
      float sc = gamma[t] * rsqrtf(var[t] + 1e-5f);
      bnA[t] = sc;
      bnB[t] = beta[t] - mean[t] * sc;
    }
  } else if (r < 1121){
    int n = (r - 593) * 128 + (t >> 1);
    int seg = t & 1;
    int plane = n / 528, m = n % 528;
    int row, col;
    if (m < 136){ row = m / 68; col = m % 68; }
    else if (m < 272){ int mm = m - 136; row = 66 + mm / 68; col = mm % 68; }
    else { int mm = m - 272; row = 2 + (mm >> 2); int c4 = mm & 3; col = (c4 & 1) + 66 * (c4 >> 1); }
    u16x8 z = {};
    *reinterpret_cast<u16x8*>(&h1p[((size_t)plane * PIMG + row * PDIM + col) * 16 + seg * 8]) = z;
  } else {
    float* wr_ = sbuf;
    float* pb  = sbuf + 256;
    const int j = r - 1121;
    wr_[t] = woff[j * 256 + t];
    __syncthreads();
    float s = 0.f;
    #pragma unroll 8
    for (int m = 0; m < 256; ++m) s += wr_[m] * w1[m * 256 + t];
    wbs[swz(256 + j, t)] = f2b(s);
    pb[t] = wr_[t] * b1[t];
    __syncthreads();
    if (t == 0){
      float bs = boff[j];
      for (int m = 0; m < 256; ++m) bs += pb[m];
      bcomb[j] = bs;
    }
  }
}

// ---------------------------------------------------------------------------
// k_gemmf: [h1 | om] = x * W^T. Register-resident A (R14 phase-0, proven),
// B streamed as pre-swizzled fragments: one contiguous 1KB load per wave per
// (o-tile, kf) -> perfectly coalesced, L1-shared across waves. NO block
// barriers in main loop. Grid 512: block = 64 px, 4 waves x 16 px.
// 11 chunks of 64 o (704, rows 688+ zero). Epilogue via per-wave C_lds.
// ---------------------------------------------------------------------------
__global__ __launch_bounds__(256, 4) void k_gemmf(const float* __restrict__ x,
    const u16* __restrict__ wbs, const float* __restrict__ b1,
    const float* __restrict__ bcomb, u16* __restrict__ h1p,
    u16* __restrict__ om){
  __shared__ __align__(16) u16 T_lds[64 * 72];     // 9216 B transpose staging
  __shared__ __align__(16) u16 C_lds[4][16 * 72];  // 9216 B per-wave epilogue

  const int t = threadIdx.x;
  const int tm = blockIdx.x * 64;
  const int b = tm >> 12, ploc = tm & 4095;
  const int lane = t & 63;
  const int w = t >> 6;
  const int lr = lane & 15, ls = lane >> 4;

  // phase 0: A into registers via LDS transpose (only barriers here)
  short8 A[8];
  const float* xs = x + (size_t)b * 256 * HW + ploc;
  #pragma unroll
  for (int rnd = 0; rnd < 4; ++rnd){
    const int kc64 = rnd * 64;
    #pragma unroll
    for (int i = 0; i < 4; ++i){
      int flat = t + i * 256;
      int c_l = flat >> 4, seg = flat & 15;
      float4 v = *reinterpret_cast<const float4*>(&xs[(size_t)(kc64 + c_l) * HW + seg * 4]);
      T_lds[(seg * 4 + 0) * 72 + c_l] = f2b(v.x);
      T_lds[(seg * 4 + 1) * 72 + c_l] = f2b(v.y);
      T_lds[(seg * 4 + 2) * 72 + c_l] = f2b(v.z);
      T_lds[(seg * 4 + 3) * 72 + c_l] = f2b(v.w);
    }
    __syncthreads();
    #pragma unroll
    for (int kk = 0; kk < 2; ++kk)
      A[rnd * 2 + kk] = *reinterpret_cast<const short8*>(
        &T_lds[(w * 16 + lr) * 72 + kk * 32 + ls * 8]);
    __syncthreads();
  }

  // main loop: 11 chunks of 64 o, barrier-free
  u16* Cw = &C_lds[w][0];
  const int pxw = tm + w * 16;

  for (int oc = 0; oc < 11; ++oc){
    const int o0 = oc * 64;
    const u16* base = wbs + (size_t)(oc * 32) * 512;   // o-tile oc*4, kf 0
    f32x4 acc[4] = {};
    #pragma unroll
    for (int kf = 0; kf < 8; ++kf){
      #pragma unroll
      for (int nf = 0; nf < 4; ++nf){
        short8 bf = *reinterpret_cast<const short8*>(base + (nf * 8 + kf) * 512 + lane * 8);
        acc[nf] = __builtin_amdgcn_mfma_f32_16x16x32_bf16(A[kf], bf, acc[nf], 0, 0, 0);
      }
    }
    __builtin_amdgcn_wave_barrier();
    #pragma unroll
    for (int nf = 0; nf < 4; ++nf){
      int o = o0 + nf * 16 + lr;
      float bi = (o < 256) ? b1[o] : ((o < 688) ? bcomb[o - 256] : 0.f);
      #pragma unroll
      for (int j = 0; j < 4; ++j)
        Cw[(ls * 4 + j) * 72 + nf * 16 + lr] = f2b(acc[nf][j] + bi);
    }
    __builtin_amdgcn_wave_barrier();
    #pragma unroll
    for (int s = 0; s < 2; ++s){
      int flat = lane + s * 64;
      int row = flat >> 3, seg = flat & 7;
      u16x8 v = *reinterpret_cast<const u16x8*>(&Cw[row * 72 + seg * 8]);
      int px = pxw + row;
      int o = o0 + seg * 8;
      if (o < 256){
        int ii = (px >> 6) & 63, jj = px & 63;
        size_t dst = ((size_t)(b * 16 + (o >> 4)) * PIMG + (ii + 2) * PDIM + jj + 2) * 16 + (o & 15);
        *reinterpret_cast<u16x8*>(&h1p[dst]) = v;
      } else if (o < 688){
        *reinterpret_cast<u16x8*>(&om[(size_t)px * MOFF + (o - 256)]) = v;
      }
    }
    __builtin_amdgcn_wave_barrier();
  }
}

// ---------------------------------------------------------------------------
// k_sample (R13/R17, proven): 4 px/block, 4-lane units, tap records,
// image->XCD swizzle, launch_bounds(256,4) — no spill.
// ---------------------------------------------------------------------------
__global__ __launch_bounds__(256, 4) void k_sample(const u16* __restrict__ h1p,
    const u16* __restrict__ om, u16* __restrict__ ydcn){
  __shared__ float oms[4 * MOFF];
  __shared__ float recs[5 * 576];
  const int t = threadIdx.x;
  const int bid = blockIdx.x;
  const int img = bid & 7;
  const int loc = bid >> 3;
  const int pblk = img * 4096 + loc * 4;
  if (t < 216){
    u16x8 v = *reinterpret_cast<const u16x8*>(&om[(size_t)pblk * MOFF + t * 8]);
    float4 lo, hi;
    lo.x = b2f(v[0]); lo.y = b2f(v[1]); lo.z = b2f(v[2]); lo.w = b2f(v[3]);
    hi.x = b2f(v[4]); hi.y = b2f(v[5]); hi.z = b2f(v[6]); hi.w = b2f(v[7]);
    *reinterpret_cast<float4*>(&oms[t * 8]) = lo;
    *reinterpret_cast<float4*>(&oms[t * 8 + 4]) = hi;
  }
  __syncthreads();

  #pragma unroll
  for (int i = 0; i < 3; ++i){
    int r = t + i * 256;
    if (i < 2 || r < 576){
      int px = r / 144, rm = r % 144;
      int g = rm / 9, k = rm % 9;
      const float* ob = &oms[px * MOFF + g * 27];
      float oh = ob[2 * k], ow = ob[2 * k + 1], m = ob[18 + k];
      int hw = (pblk + px) & 4095;
      float ph = (float)((hw >> 6) + k / 3 - 1) + oh;
      float pw = (float)((hw & 63) + k % 3 - 1) + ow;
      float h0f = floorf(ph), w0f = floorf(pw);
      float ah = ph - h0f, aw = pw - w0f;
      int h0 = (int)h0f, w0 = (int)w0f;
      int hc = min(max(h0, -2), 64) + 2;
      int wc = min(max(w0, -2), 64) + 2;
      float mh1 = m * ah, mh0 = m - mh1;
      float c01 = mh0 * aw, c00 = mh0 - c01;
      float c11 = mh1 * aw, c10 = mh1 - c11;
      recs[r]            = c00;
      recs[576 + r]      = c01;
      recs[1152 + r]     = c10;
      recs[1728 + r]     = c11;
      recs[2304 + r]     = __uint_as_float((unsigned)((hc * PDIM + wc) << 5));
    }
  }
  __syncthreads();

  const int px = t >> 6;
  const int g = (t >> 2) & 15;
  const int q = t & 3;
  const int p = pblk + px;
  const int xsel = q >> 1;
  const u16* lanebase = h1p + (size_t)(img * 16 + g) * PIMG * 16 + q * 8;
  const int ri = px * 144 + g * 9;
  const float* ctp = &recs[xsel * 576 + ri];
  const float* cbp = &recs[1152 + xsel * 576 + ri];
  const float* adp = &recs[2304 + ri];

  float acc[8] = {};
  #pragma unroll
  for (int k = 0; k < 9; ++k){
    float ct = ctp[k];
    float cb = cbp[k];
    unsigned off = __float_as_uint(adp[k]);
    const u16* c0 = (const u16*)((const char*)lanebase + off);
    u16x8 tv = *reinterpret_cast<const u16x8*>(c0);
    u16x8 bv = *reinterpret_cast<const u16x8*>(c0 + PDIM * 16);
    #pragma unroll
    for (int j = 0; j < 8; ++j)
      acc[j] += ct * b2f(tv[j]) + cb * b2f(bv[j]);
  }
  #pragma unroll
  for (int j = 0; j < 8; ++j)
    acc[j] += __shfl_xor(acc[j], 2, 64);
  if (q < 2){
    u16x8 o8;
    #pragma unroll
    for (int j = 0; j < 8; ++j) o8[j] = f2b(acc[j]);
    *reinterpret_cast<u16x8*>(&ydcn[(size_t)p * 256 + g * 16 + q * 8]) = o8;
  }
}

// ---------------------------------------------------------------------------
// k_gemm2f: conv2 + BN + SiLU. Register-resident A from ydcn (LDS transpose
// phase 0), pre-swizzled wb2s fragments -> barrier-free main loop, direct
// f32x4 BN+SiLU stores. Grid 512: block = 64 px, 4 waves x 16 px.
// ---------------------------------------------------------------------------
__global__ __launch_bounds__(256, 4) void k_gemm2f(const u16* __restrict__ ydcn,
    const u16* __restrict__ wb2s, const float* __restrict__ bnA,
    const float* __restrict__ bnB, float* __restrict__ out){
  __shared__ __align__(16) u16 T_lds[64 * 72];

  const int t = threadIdx.x;
  const int tm = blockIdx.x * 64;
  const int b = tm >> 12, ploc = tm & 4095;
  const int lane = t & 63;
  const int w = t >> 6;
  const int lr = lane & 15, ls = lane >> 4;

  // phase 0: A frags from ydcn (bf16 row-major, coalesced u16x8 staging)
  short8 A[8];
  #pragma unroll
  for (int rnd = 0; rnd < 4; ++rnd){
    const int kc64 = rnd * 64;
    #pragma unroll
    for (int i = 0; i < 2; ++i){
      int u = t + i * 256;
      int row = u >> 3, seg = u & 7;
      *reinterpret_cast<u16x8*>(&T_lds[row * 72 + seg * 8]) =
        *reinterpret_cast<const u16x8*>(&ydcn[(size_t)(tm + row) * 256 + kc64 + seg * 8]);
    }
    __syncthreads();
    #pragma unroll
    for (int kk = 0; kk < 2; ++kk)
      A[rnd * 2 + kk] = *reinterpret_cast<const short8*>(
        &T_lds[(w * 16 + lr) * 72 + kk * 32 + ls * 8]);
    __syncthreads();
  }

  // main: 4 groups of 4 o-tiles, barrier-free
  #pragma unroll
  for (int g = 0; g < 4; ++g){
    const u16* base = wb2s + (size_t)(g * 32) * 512;
    f32x4 acc[4] = {};
    #pragma unroll
    for (int kf = 0; kf < 8; ++kf){
      #pragma unroll
      for (int nf = 0; nf < 4; ++nf){
        short8 bf = *reinterpret_cast<const short8*>(base + (nf * 8 + kf) * 512 + lane * 8);
        acc[nf] = __builtin_amdgcn_mfma_f32_16x16x32_bf16(A[kf], bf, acc[nf], 0, 0, 0);
      }
    }
    #pragma unroll
    for (int nf = 0; nf < 4; ++nf){
      int o = (g * 4 + nf) * 16 + lr;
      float sA = bnA[o], sB = bnB[o];
      f32x4 st;
      #pragma unroll
      for (int j = 0; j < 4; ++j){
        float y = acc[nf][j] * sA + sB;
        st[j] = y / (1.f + expf(-y));
      }
      *reinterpret_cast<f32x4*>(&out[((size_t)(b * 256 + o)) * HW + ploc + w * 16 + ls * 4]) = st;
    }
  }
}

extern "C" void kernel_launch(void* const* d_in, const int* in_sizes, int n_in,
                              void* d_out, int out_size, void* d_ws, size_t ws_size,
                              hipStream_t stream) {
  const float* x     = (const float*)d_in[0];
  const float* w1    = (const float*)d_in[1];
  const float* b1    = (const float*)d_in[2];
  const float* woff  = (const float*)d_in[3];
  const float* boff  = (const float*)d_in[4];
  const float* w2    = (const float*)d_in[5];
  const float* gamma = (const float*)d_in[6];
  const float* beta  = (const float*)d_in[7];
  const float* mean  = (const float*)d_in[8];
  const float* var   = (const float*)d_in[9];
  float* out = (float*)d_out;
  (void)in_sizes; (void)n_in; (void)out_size; (void)ws_size;

  u16* h1p   = (u16*)d_ws;                                // 128 planes * 4624 * 32B = 18.9 MB
  u16* om    = h1p + (size_t)128 * PIMG * 16;             // 32768*432 = 28.3 MB
  u16* ydcn  = om + (size_t)PTOT * MOFF;                  // 32768*256 = 16.8 MB
  u16* wbs   = ydcn + (size_t)PTOT * CCH;                 // 768*256 u16 swizzled
  u16* wb2s  = wbs + 768 * 256;                           // 256*256 u16 swizzled
  float* bnA = (float*)(wb2s + 256 * 256);
  float* bnB = bnA + 256;
  float* bcomb = bnB + 256;                               // 432 f32

  dim3 blk(256);
  k_prep<<<dim3(1553), blk, 0, stream>>>(w1, w2, woff, b1, boff,
                                         gamma, beta, mean, var,
                                         wbs, wb2s, bnA, bnB, bcomb, h1p);
  k_gemmf<<<dim3(512), blk, 0, stream>>>(x, wbs, b1, bcomb, h1p, om);
  k_sample<<<dim3(PTOT / 4), blk, 0, stream>>>(h1p, om, ydcn);
  k_gemm2f<<<dim3(512), blk, 0, stream>>>(ydcn, wb2s, bnA, bnB, out);
}